// Round 1
// baseline (1141.867 us; speedup 1.0000x reference)
//
#include <hip/hip_runtime.h>
#include <hip/hip_bf16.h>
#include <stdint.h>

#define T_TOK 8192
#define D_DIM 1024
#define E_NUM 8
#define H_DIM 4096
#define NPAIR (T_TOK * 2)

typedef short bf16x8 __attribute__((ext_vector_type(8)));
typedef float f32x4 __attribute__((ext_vector_type(4)));
typedef unsigned short usv8 __attribute__((ext_vector_type(8)));

#define AS1 __attribute__((address_space(1)))
#define AS3 __attribute__((address_space(3)))

__device__ __forceinline__ unsigned short f2b(float f) {
  union { float f; uint32_t u; } v; v.f = f;
  uint32_t r = (v.u + 0x7fffu + ((v.u >> 16) & 1u)) >> 16;
  return (unsigned short)r;
}

__device__ __forceinline__ float gelu_tanh(float x) {
  float u = 0.7978845608028654f * (x + 0.044715f * x * x * x);
  u = fminf(fmaxf(u, -15.f), 15.f);
  float e = __expf(2.f * u);
  float t = (e - 1.f) / (e + 1.f);
  return 0.5f * x * (1.f + t);
}

__device__ __forceinline__ void gload_lds16(const void* g, void* l) {
  __builtin_amdgcn_global_load_lds((const AS1 uint32_t*)g, (AS3 uint32_t*)l, 16, 0, 0);
}

// ---------------- fp32 -> bf16 convert (x) ----------------
__global__ __launch_bounds__(256) void moe_conv_bf16(const float* __restrict__ in,
                                                     unsigned short* __restrict__ out, int n) {
  int i = (blockIdx.x * 256 + threadIdx.x) * 8;
  if (i >= n) return;
  float4 a = *(const float4*)(in + i);
  float4 b = *(const float4*)(in + i + 4);
  usv8 r;
  r[0] = f2b(a.x); r[1] = f2b(a.y); r[2] = f2b(a.z); r[3] = f2b(a.w);
  r[4] = f2b(b.x); r[5] = f2b(b.y); r[6] = f2b(b.z); r[7] = f2b(b.w);
  *(usv8*)(out + i) = r;
}

// ---------------- transpose + convert: in [E][R][C] f32 -> out [E][C][R] bf16 ----------------
__global__ __launch_bounds__(256) void moe_transpose(const float* __restrict__ in,
                                                     unsigned short* __restrict__ out,
                                                     int R, int C) {
  int e = blockIdx.z;
  int c0 = blockIdx.x * 64, r0 = blockIdx.y * 64;
  __shared__ float tile[64][65];
  const float* ine = in + (size_t)e * R * C;
  unsigned short* oute = out + (size_t)e * R * C;
  int tr = threadIdx.x >> 2;
  int tc4 = (threadIdx.x & 3) * 16;
#pragma unroll
  for (int p = 0; p < 4; p++) {
    int c = tc4 + p * 4;
    float4 v = *(const float4*)(ine + (size_t)(r0 + tr) * C + c0 + c);
    tile[tr][c] = v.x; tile[tr][c + 1] = v.y; tile[tr][c + 2] = v.z; tile[tr][c + 3] = v.w;
  }
  __syncthreads();
#pragma unroll
  for (int p = 0; p < 4; p++) {
    int rr = tc4 + p * 4;
    ushort4 o;
    o.x = f2b(tile[rr + 0][tr]);
    o.y = f2b(tile[rr + 1][tr]);
    o.z = f2b(tile[rr + 2][tr]);
    o.w = f2b(tile[rr + 3][tr]);
    *(ushort4*)(oute + (size_t)(c0 + tr) * R + r0 + rr) = o;
  }
}

// ---------------- gating: logits, top-2, softmax, counts ----------------
__global__ __launch_bounds__(256) void moe_gate(const float* __restrict__ x,
                                                const float* __restrict__ gw,
                                                const float* __restrict__ gb,
                                                int2* __restrict__ sel,
                                                float2* __restrict__ wts,
                                                int* __restrict__ meta) {
  int lane = threadIdx.x & 63;
  int t = blockIdx.x * 4 + (threadIdx.x >> 6);
  const float* xr = x + (size_t)t * D_DIM;
  float acc[8];
#pragma unroll
  for (int e = 0; e < 8; e++) acc[e] = 0.f;
#pragma unroll
  for (int i = 0; i < 4; i++) {
    int d0 = lane * 4 + i * 256;
    float4 xv = *(const float4*)(xr + d0);
    const float* gp = gw + (size_t)d0 * 8;
    float xs[4] = {xv.x, xv.y, xv.z, xv.w};
#pragma unroll
    for (int j = 0; j < 4; j++) {
#pragma unroll
      for (int e = 0; e < 8; e++) acc[e] += xs[j] * gp[j * 8 + e];
    }
  }
#pragma unroll
  for (int off = 32; off > 0; off >>= 1) {
#pragma unroll
    for (int e = 0; e < 8; e++) acc[e] += __shfl_xor(acc[e], off);
  }
  if (lane == 0) {
    float lg[8];
#pragma unroll
    for (int e = 0; e < 8; e++) lg[e] = acc[e] + gb[e];
    int e0 = 0; float b0 = lg[0];
#pragma unroll
    for (int e = 1; e < 8; e++) if (lg[e] > b0) { b0 = lg[e]; e0 = e; }
    int e1 = -1; float b1v = -1e30f;
#pragma unroll
    for (int e = 0; e < 8; e++) if (e != e0 && lg[e] > b1v) { b1v = lg[e]; e1 = e; }
    float d = __expf(b1v - b0);
    float w0 = 1.f / (1.f + d), w1 = d / (1.f + d);
    sel[t] = make_int2(e0, e1);
    wts[t] = make_float2(w0, w1);
    atomicAdd(&meta[e0], 1);
    atomicAdd(&meta[e1], 1);
  }
}

// meta layout: [0..7] counts, [8..16] offsets, [20..27] cursor
__global__ void moe_scan(int* meta) {
  if (threadIdx.x == 0 && blockIdx.x == 0) {
    int o = 0;
    for (int e = 0; e < 8; e++) { meta[8 + e] = o; meta[20 + e] = o; o += meta[e]; }
    meta[16] = o;
  }
}

__global__ __launch_bounds__(256) void moe_scatter(const int2* __restrict__ sel,
                                                   const float2* __restrict__ wts,
                                                   int* __restrict__ meta,
                                                   int* __restrict__ token_id,
                                                   float* __restrict__ weightv) {
  int t = blockIdx.x * 256 + threadIdx.x;
  if (t >= T_TOK) return;
  int2 s = sel[t];
  float2 w = wts[t];
  int p0 = atomicAdd(&meta[20 + s.x], 1); token_id[p0] = t; weightv[p0] = w.x;
  int p1 = atomicAdd(&meta[20 + s.y], 1); token_id[p1] = t; weightv[p1] = w.y;
}

// ---------------- GEMM1: h[p,:] = gelu(x[tok[p]] @ w1[e] + b1[e]), bf16 out ----------------
__global__ __launch_bounds__(256) void moe_gemm1(const unsigned short* __restrict__ xb,
                                                 const unsigned short* __restrict__ w1t,
                                                 const float* __restrict__ b1,
                                                 const int* __restrict__ meta,
                                                 const int* __restrict__ token_id,
                                                 unsigned short* __restrict__ hbuf) {
  int e = blockIdx.z;
  int seg = meta[8 + e], ne = meta[9 + e] - seg;
  int m0 = blockIdx.x * 128;
  if (m0 >= ne) return;
  int n0 = blockIdx.y * 128;
  const unsigned short* wB = w1t + (size_t)e * H_DIM * D_DIM;  // [H][D] bf16

  __shared__ unsigned short As[2][4096];
  __shared__ unsigned short Bs[2][4096];

  int tid = threadIdx.x, lane = tid & 63, wv = tid >> 6;
  const unsigned short* aptr[2];
  const unsigned short* bptr[2];
#pragma unroll
  for (int q = 0; q < 2; q++) {
    int chunk = (wv + 4 * q) * 64 + lane;
    int row = chunk >> 2;
    int ko = (chunk & 3) * 8;
    int gi = m0 + row; if (gi >= ne) gi = m0;
    int tok = token_id[seg + gi];
    aptr[q] = xb + (size_t)tok * D_DIM + ko;
    bptr[q] = wB + (size_t)(n0 + row) * D_DIM + ko;
  }
  auto stage = [&](int buf, int kt) {
#pragma unroll
    for (int q = 0; q < 2; q++) {
      gload_lds16(aptr[q] + kt * 32, &As[buf][(wv + 4 * q) * 512]);
      gload_lds16(bptr[q] + kt * 32, &Bs[buf][(wv + 4 * q) * 512]);
    }
  };

  f32x4 acc[4][4] = {};
  int wr = wv >> 1, wc = wv & 1;
  int abase = (wr * 64 + (lane & 15)) * 32 + (lane >> 4) * 8;
  int bbase = (wc * 64 + (lane & 15)) * 32 + (lane >> 4) * 8;

  stage(0, 0);
  __syncthreads();
  const int nk = D_DIM / 32;
  for (int kt = 0; kt < nk; ++kt) {
    int cur = kt & 1;
    if (kt + 1 < nk) stage(cur ^ 1, kt + 1);
    bf16x8 af[4], bfr[4];
#pragma unroll
    for (int m = 0; m < 4; m++) af[m] = *(const bf16x8*)&As[cur][abase + m * 512];
#pragma unroll
    for (int n = 0; n < 4; n++) bfr[n] = *(const bf16x8*)&Bs[cur][bbase + n * 512];
#pragma unroll
    for (int m = 0; m < 4; m++)
#pragma unroll
      for (int n = 0; n < 4; n++)
        acc[m][n] = __builtin_amdgcn_mfma_f32_16x16x32_bf16(af[m], bfr[n], acc[m][n], 0, 0, 0);
    __syncthreads();
  }

  int rbase = wr * 64 + (lane >> 4) * 4;
  int cbase = n0 + wc * 64 + (lane & 15);
  const float* b1e = b1 + (size_t)e * H_DIM + cbase;
  float bv[4];
#pragma unroll
  for (int n = 0; n < 4; n++) bv[n] = b1e[n * 16];
#pragma unroll
  for (int m = 0; m < 4; m++) {
#pragma unroll
    for (int j = 0; j < 4; j++) {
      int gi = m0 + rbase + m * 16 + j;
      if (gi < ne) {
        unsigned short* hrow = hbuf + (size_t)(seg + gi) * H_DIM + cbase;
#pragma unroll
        for (int n = 0; n < 4; n++) {
          float v = acc[m][n][j] + bv[n];
          hrow[n * 16] = f2b(gelu_tanh(v));
        }
      }
    }
  }
}

// ---------------- GEMM2: out[tok[p],:] += w_p * (h[p,:] @ w2[e] + b2[e]) ----------------
__global__ __launch_bounds__(256) void moe_gemm2(const unsigned short* __restrict__ hbuf,
                                                 const unsigned short* __restrict__ w2t,
                                                 const float* __restrict__ b2,
                                                 const int* __restrict__ meta,
                                                 const int* __restrict__ token_id,
                                                 const float* __restrict__ weightv,
                                                 float* __restrict__ out) {
  int e = blockIdx.z;
  int seg = meta[8 + e], ne = meta[9 + e] - seg;
  int m0 = blockIdx.x * 128;
  if (m0 >= ne) return;
  int n0 = blockIdx.y * 128;
  const unsigned short* wB = w2t + (size_t)e * D_DIM * H_DIM;  // [D][H] bf16

  __shared__ unsigned short As[2][4096];
  __shared__ unsigned short Bs[2][4096];

  int tid = threadIdx.x, lane = tid & 63, wv = tid >> 6;
  const unsigned short* aptr[2];
  const unsigned short* bptr[2];
#pragma unroll
  for (int q = 0; q < 2; q++) {
    int chunk = (wv + 4 * q) * 64 + lane;
    int row = chunk >> 2;
    int ko = (chunk & 3) * 8;
    int gi = m0 + row; if (gi >= ne) gi = m0;
    aptr[q] = hbuf + (size_t)(seg + gi) * H_DIM + ko;
    bptr[q] = wB + (size_t)(n0 + row) * H_DIM + ko;
  }
  auto stage = [&](int buf, int kt) {
#pragma unroll
    for (int q = 0; q < 2; q++) {
      gload_lds16(aptr[q] + kt * 32, &As[buf][(wv + 4 * q) * 512]);
      gload_lds16(bptr[q] + kt * 32, &Bs[buf][(wv + 4 * q) * 512]);
    }
  };

  f32x4 acc[4][4] = {};
  int wr = wv >> 1, wc = wv & 1;
  int abase = (wr * 64 + (lane & 15)) * 32 + (lane >> 4) * 8;
  int bbase = (wc * 64 + (lane & 15)) * 32 + (lane >> 4) * 8;

  stage(0, 0);
  __syncthreads();
  const int nk = H_DIM / 32;
  for (int kt = 0; kt < nk; ++kt) {
    int cur = kt & 1;
    if (kt + 1 < nk) stage(cur ^ 1, kt + 1);
    bf16x8 af[4], bfr[4];
#pragma unroll
    for (int m = 0; m < 4; m++) af[m] = *(const bf16x8*)&As[cur][abase + m * 512];
#pragma unroll
    for (int n = 0; n < 4; n++) bfr[n] = *(const bf16x8*)&Bs[cur][bbase + n * 512];
#pragma unroll
    for (int m = 0; m < 4; m++)
#pragma unroll
      for (int n = 0; n < 4; n++)
        acc[m][n] = __builtin_amdgcn_mfma_f32_16x16x32_bf16(af[m], bfr[n], acc[m][n], 0, 0, 0);
    __syncthreads();
  }

  int rbase = wr * 64 + (lane >> 4) * 4;
  int cbase = n0 + wc * 64 + (lane & 15);
  const float* b2e = b2 + (size_t)e * D_DIM + cbase;
  float bv[4];
#pragma unroll
  for (int n = 0; n < 4; n++) bv[n] = b2e[n * 16];
#pragma unroll
  for (int m = 0; m < 4; m++) {
#pragma unroll
    for (int j = 0; j < 4; j++) {
      int gi = m0 + rbase + m * 16 + j;
      if (gi < ne) {
        int p = seg + gi;
        int tok = token_id[p];
        float wt = weightv[p];
        float* orow = out + (size_t)tok * D_DIM + cbase;
#pragma unroll
        for (int n = 0; n < 4; n++)
          atomicAdd(&orow[n * 16], wt * (acc[m][n][j] + bv[n]));
      }
    }
  }
}

extern "C" void kernel_launch(void* const* d_in, const int* in_sizes, int n_in,
                              void* d_out, int out_size, void* d_ws, size_t ws_size,
                              hipStream_t stream) {
  const float* x      = (const float*)d_in[0];
  const float* gate_w = (const float*)d_in[1];
  const float* gate_b = (const float*)d_in[2];
  const float* w1     = (const float*)d_in[3];
  const float* b1     = (const float*)d_in[4];
  const float* w2     = (const float*)d_in[5];
  const float* b2     = (const float*)d_in[6];
  float* out = (float*)d_out;

  uint8_t* ws = (uint8_t*)d_ws;
  unsigned short* hbuf = (unsigned short*)(ws);                 // 16384*4096*2 = 134217728
  unsigned short* xb   = (unsigned short*)(ws + 134217728ull);  // 16777216
  unsigned short* w1t  = (unsigned short*)(ws + 150994944ull);  // 67108864
  unsigned short* w2t  = (unsigned short*)(ws + 218103808ull);  // 67108864
  int*    token_id = (int*)  (ws + 285212672ull);               // 65536
  float*  weightv  = (float*)(ws + 285278208ull);               // 65536
  int2*   sel      = (int2*) (ws + 285343744ull);               // 65536
  float2* wts      = (float2*)(ws + 285409280ull);              // 65536
  int*    meta     = (int*)  (ws + 285474816ull);               // 128

  hipMemsetAsync(meta, 0, 128, stream);
  hipMemsetAsync(out, 0, (size_t)T_TOK * D_DIM * sizeof(float), stream);

  moe_conv_bf16<<<dim3((T_TOK * D_DIM) / (256 * 8)), 256, 0, stream>>>(x, xb, T_TOK * D_DIM);
  moe_transpose<<<dim3(H_DIM / 64, D_DIM / 64, E_NUM), 256, 0, stream>>>(w1, w1t, D_DIM, H_DIM);
  moe_transpose<<<dim3(D_DIM / 64, H_DIM / 64, E_NUM), 256, 0, stream>>>(w2, w2t, H_DIM, D_DIM);
  moe_gate<<<dim3(T_TOK / 4), 256, 0, stream>>>(x, gate_w, gate_b, sel, wts, meta);
  moe_scan<<<1, 64, 0, stream>>>(meta);
  moe_scatter<<<dim3(T_TOK / 256), 256, 0, stream>>>(sel, wts, meta, token_id, weightv);
  moe_gemm1<<<dim3(64, H_DIM / 128, E_NUM), 256, 0, stream>>>(xb, w1t, b1, meta, token_id, hbuf);
  moe_gemm2<<<dim3(64, D_DIM / 128, E_NUM), 256, 0, stream>>>(hbuf, w2t, b2, meta, token_id, weightv, out);
}

// Round 2
// 878.760 us; speedup vs baseline: 1.2994x; 1.2994x over previous
//
#include <hip/hip_runtime.h>
#include <hip/hip_bf16.h>
#include <stdint.h>

#define T_TOK 8192
#define D_DIM 1024
#define E_NUM 8
#define H_DIM 4096
#define WL_MAX 136

typedef short bf16x8 __attribute__((ext_vector_type(8)));
typedef float f32x4 __attribute__((ext_vector_type(4)));
typedef unsigned short usv8 __attribute__((ext_vector_type(8)));

#define AS1 __attribute__((address_space(1)))
#define AS3 __attribute__((address_space(3)))

__device__ __forceinline__ unsigned short f2b(float f) {
  union { float f; uint32_t u; } v; v.f = f;
  uint32_t r = (v.u + 0x7fffu + ((v.u >> 16) & 1u)) >> 16;
  return (unsigned short)r;
}

__device__ __forceinline__ float gelu_tanh(float x) {
  float u = 0.7978845608028654f * (x + 0.044715f * x * x * x);
  u = fminf(fmaxf(u, -15.f), 15.f);
  float e = __expf(2.f * u);
  float t = (e - 1.f) / (e + 1.f);
  return 0.5f * x * (1.f + t);
}

__device__ __forceinline__ void gload_lds16(const void* g, void* l) {
  __builtin_amdgcn_global_load_lds((const AS1 uint32_t*)g, (AS3 uint32_t*)l, 16, 0, 0);
}

// ---------------- gate + x->bf16 conversion fused ----------------
__global__ __launch_bounds__(256) void moe_gate_conv(const float* __restrict__ x,
                                                     const float* __restrict__ gw,
                                                     const float* __restrict__ gb,
                                                     unsigned short* __restrict__ xb,
                                                     int2* __restrict__ sel,
                                                     float2* __restrict__ wts,
                                                     int* __restrict__ meta) {
  int lane = threadIdx.x & 63;
  int t = blockIdx.x * 4 + (threadIdx.x >> 6);
  const float* xr = x + (size_t)t * D_DIM;
  unsigned short* xo = xb + (size_t)t * D_DIM;
  float acc[8];
#pragma unroll
  for (int e = 0; e < 8; e++) acc[e] = 0.f;
#pragma unroll
  for (int i = 0; i < 4; i++) {
    int d0 = lane * 4 + i * 256;
    float4 xv = *(const float4*)(xr + d0);
    ushort4 o;
    o.x = f2b(xv.x); o.y = f2b(xv.y); o.z = f2b(xv.z); o.w = f2b(xv.w);
    *(ushort4*)(xo + d0) = o;
    const float* gp = gw + (size_t)d0 * 8;
    float xs[4] = {xv.x, xv.y, xv.z, xv.w};
#pragma unroll
    for (int j = 0; j < 4; j++) {
#pragma unroll
      for (int e = 0; e < 8; e++) acc[e] += xs[j] * gp[j * 8 + e];
    }
  }
#pragma unroll
  for (int off = 32; off > 0; off >>= 1) {
#pragma unroll
    for (int e = 0; e < 8; e++) acc[e] += __shfl_xor(acc[e], off);
  }
  if (lane == 0) {
    float lg[8];
#pragma unroll
    for (int e = 0; e < 8; e++) lg[e] = acc[e] + gb[e];
    int e0 = 0; float b0 = lg[0];
#pragma unroll
    for (int e = 1; e < 8; e++) if (lg[e] > b0) { b0 = lg[e]; e0 = e; }
    int e1 = -1; float b1v = -1e30f;
#pragma unroll
    for (int e = 0; e < 8; e++) if (e != e0 && lg[e] > b1v) { b1v = lg[e]; e1 = e; }
    float d = __expf(b1v - b0);
    float w0 = 1.f / (1.f + d), w1 = d / (1.f + d);
    sel[t] = make_int2(e0, e1);
    wts[t] = make_float2(w0, w1);
    atomicAdd(&meta[e0], 1);
    atomicAdd(&meta[e1], 1);
  }
}

// ---------------- transpose + convert: in [E][R][C] f32 -> out [E][C][R] bf16 ----------------
__global__ __launch_bounds__(256) void moe_transpose(const float* __restrict__ in,
                                                     unsigned short* __restrict__ out,
                                                     int R, int C) {
  int e = blockIdx.z;
  int c0 = blockIdx.x * 64, r0 = blockIdx.y * 64;
  __shared__ float tile[64][65];
  const float* ine = in + (size_t)e * R * C;
  unsigned short* oute = out + (size_t)e * R * C;
  int tr = threadIdx.x >> 2;
  int tc4 = (threadIdx.x & 3) * 16;
#pragma unroll
  for (int p = 0; p < 4; p++) {
    int c = tc4 + p * 4;
    float4 v = *(const float4*)(ine + (size_t)(r0 + tr) * C + c0 + c);
    tile[tr][c] = v.x; tile[tr][c + 1] = v.y; tile[tr][c + 2] = v.z; tile[tr][c + 3] = v.w;
  }
  __syncthreads();
#pragma unroll
  for (int p = 0; p < 4; p++) {
    int rr = tc4 + p * 4;
    ushort4 o;
    o.x = f2b(tile[rr + 0][tr]);
    o.y = f2b(tile[rr + 1][tr]);
    o.z = f2b(tile[rr + 2][tr]);
    o.w = f2b(tile[rr + 3][tr]);
    *(ushort4*)(oute + (size_t)(c0 + tr) * R + r0 + rr) = o;
  }
}

// meta layout: [0..7] counts, [8..16] offsets(+total), [17] wl_count, [20..27] cursor
__global__ void moe_scan(int* meta, int2* wl) {
  if (threadIdx.x == 0 && blockIdx.x == 0) {
    int o = 0;
    for (int e = 0; e < 8; e++) { meta[8 + e] = o; meta[20 + e] = o; o += meta[e]; }
    meta[16] = o;
    int w = 0;
    for (int e = 0; e < 8; e++)
      for (int m0 = 0; m0 < meta[e]; m0 += 128) wl[w++] = make_int2(e, m0);
    meta[17] = w;
  }
}

__global__ __launch_bounds__(256) void moe_scatter(const int2* __restrict__ sel,
                                                   int* __restrict__ meta,
                                                   int* __restrict__ token_id,
                                                   int2* __restrict__ pos) {
  int t = blockIdx.x * 256 + threadIdx.x;
  if (t >= T_TOK) return;
  int2 s = sel[t];
  int p0 = atomicAdd(&meta[20 + s.x], 1); token_id[p0] = t;
  int p1 = atomicAdd(&meta[20 + s.y], 1); token_id[p1] = t;
  pos[t] = make_int2(p0, p1);
}

// ---------------- GEMM1: h[p,:] = gelu(x[tok[p]] @ w1[e] + b1[e]), bf16 out ----------------
__global__ __launch_bounds__(256) void moe_gemm1(const unsigned short* __restrict__ xb,
                                                 const unsigned short* __restrict__ w1t,
                                                 const float* __restrict__ b1,
                                                 const int* __restrict__ meta,
                                                 const int2* __restrict__ wl,
                                                 const int* __restrict__ token_id,
                                                 unsigned short* __restrict__ hbuf) {
  int wi = blockIdx.y;
  if (wi >= meta[17]) return;
  int e = wl[wi].x, m0 = wl[wi].y;
  int seg = meta[8 + e], ne = meta[9 + e] - seg;
  int n0 = blockIdx.x * 128;
  const unsigned short* wB = w1t + (size_t)e * H_DIM * D_DIM;  // [H][D] bf16

  __shared__ unsigned short As[2][4096];
  __shared__ unsigned short Bs[2][4096];

  int tid = threadIdx.x, lane = tid & 63, wv = tid >> 6;
  const unsigned short* aptr[2];
  const unsigned short* bptr[2];
#pragma unroll
  for (int q = 0; q < 2; q++) {
    int chunk = (wv + 4 * q) * 64 + lane;
    int row = chunk >> 2;
    int ko = (chunk & 3) * 8;
    int gi = m0 + row; if (gi >= ne) gi = m0;
    int tok = token_id[seg + gi];
    aptr[q] = xb + (size_t)tok * D_DIM + ko;
    bptr[q] = wB + (size_t)(n0 + row) * D_DIM + ko;
  }
  auto stage = [&](int buf, int kt) {
#pragma unroll
    for (int q = 0; q < 2; q++) {
      gload_lds16(aptr[q] + kt * 32, &As[buf][(wv + 4 * q) * 512]);
      gload_lds16(bptr[q] + kt * 32, &Bs[buf][(wv + 4 * q) * 512]);
    }
  };

  f32x4 acc[4][4] = {};
  int wr = wv >> 1, wc = wv & 1;
  int abase = (wr * 64 + (lane & 15)) * 32 + (lane >> 4) * 8;
  int bbase = (wc * 64 + (lane & 15)) * 32 + (lane >> 4) * 8;

  stage(0, 0);
  __syncthreads();
  const int nk = D_DIM / 32;
  for (int kt = 0; kt < nk; ++kt) {
    int cur = kt & 1;
    if (kt + 1 < nk) stage(cur ^ 1, kt + 1);
    bf16x8 af[4], bfr[4];
#pragma unroll
    for (int m = 0; m < 4; m++) af[m] = *(const bf16x8*)&As[cur][abase + m * 512];
#pragma unroll
    for (int n = 0; n < 4; n++) bfr[n] = *(const bf16x8*)&Bs[cur][bbase + n * 512];
#pragma unroll
    for (int m = 0; m < 4; m++)
#pragma unroll
      for (int n = 0; n < 4; n++)
        acc[m][n] = __builtin_amdgcn_mfma_f32_16x16x32_bf16(af[m], bfr[n], acc[m][n], 0, 0, 0);
    __syncthreads();
  }

  int rbase = wr * 64 + (lane >> 4) * 4;
  int cbase = n0 + wc * 64 + (lane & 15);
  const float* b1e = b1 + (size_t)e * H_DIM + cbase;
  float bv[4];
#pragma unroll
  for (int n = 0; n < 4; n++) bv[n] = b1e[n * 16];
#pragma unroll
  for (int m = 0; m < 4; m++) {
#pragma unroll
    for (int j = 0; j < 4; j++) {
      int gi = m0 + rbase + m * 16 + j;
      if (gi < ne) {
        unsigned short* hrow = hbuf + (size_t)(seg + gi) * H_DIM + cbase;
#pragma unroll
        for (int n = 0; n < 4; n++) {
          float v = acc[m][n][j] + bv[n];
          hrow[n * 16] = f2b(gelu_tanh(v));
        }
      }
    }
  }
}

// ---------------- GEMM2: y[p,:] = h[p,:] @ w2[e] + b2[e]  (pair-major fp32, no atomics) --------
__global__ __launch_bounds__(256) void moe_gemm2(const unsigned short* __restrict__ hbuf,
                                                 const unsigned short* __restrict__ w2t,
                                                 const float* __restrict__ b2,
                                                 const int* __restrict__ meta,
                                                 const int2* __restrict__ wl,
                                                 float* __restrict__ y) {
  int wi = blockIdx.y;
  if (wi >= meta[17]) return;
  int e = wl[wi].x, m0 = wl[wi].y;
  int seg = meta[8 + e], ne = meta[9 + e] - seg;
  int n0 = blockIdx.x * 128;
  const unsigned short* wB = w2t + (size_t)e * D_DIM * H_DIM;  // [D][H] bf16

  __shared__ unsigned short As[2][4096];
  __shared__ unsigned short Bs[2][4096];

  int tid = threadIdx.x, lane = tid & 63, wv = tid >> 6;
  const unsigned short* aptr[2];
  const unsigned short* bptr[2];
#pragma unroll
  for (int q = 0; q < 2; q++) {
    int chunk = (wv + 4 * q) * 64 + lane;
    int row = chunk >> 2;
    int ko = (chunk & 3) * 8;
    int gi = m0 + row; if (gi >= ne) gi = m0;
    aptr[q] = hbuf + (size_t)(seg + gi) * H_DIM + ko;
    bptr[q] = wB + (size_t)(n0 + row) * H_DIM + ko;
  }
  auto stage = [&](int buf, int kt) {
#pragma unroll
    for (int q = 0; q < 2; q++) {
      gload_lds16(aptr[q] + kt * 32, &As[buf][(wv + 4 * q) * 512]);
      gload_lds16(bptr[q] + kt * 32, &Bs[buf][(wv + 4 * q) * 512]);
    }
  };

  f32x4 acc[4][4] = {};
  int wr = wv >> 1, wc = wv & 1;
  int abase = (wr * 64 + (lane & 15)) * 32 + (lane >> 4) * 8;
  int bbase = (wc * 64 + (lane & 15)) * 32 + (lane >> 4) * 8;

  stage(0, 0);
  __syncthreads();
  const int nk = H_DIM / 32;
  for (int kt = 0; kt < nk; ++kt) {
    int cur = kt & 1;
    if (kt + 1 < nk) stage(cur ^ 1, kt + 1);
    bf16x8 af[4], bfr[4];
#pragma unroll
    for (int m = 0; m < 4; m++) af[m] = *(const bf16x8*)&As[cur][abase + m * 512];
#pragma unroll
    for (int n = 0; n < 4; n++) bfr[n] = *(const bf16x8*)&Bs[cur][bbase + n * 512];
#pragma unroll
    for (int m = 0; m < 4; m++)
#pragma unroll
      for (int n = 0; n < 4; n++)
        acc[m][n] = __builtin_amdgcn_mfma_f32_16x16x32_bf16(af[m], bfr[n], acc[m][n], 0, 0, 0);
    __syncthreads();
  }

  int rbase = wr * 64 + (lane >> 4) * 4;
  int cbase = n0 + wc * 64 + (lane & 15);
  const float* b2e = b2 + (size_t)e * D_DIM + cbase;
  float bv[4];
#pragma unroll
  for (int n = 0; n < 4; n++) bv[n] = b2e[n * 16];
#pragma unroll
  for (int m = 0; m < 4; m++) {
#pragma unroll
    for (int j = 0; j < 4; j++) {
      int gi = m0 + rbase + m * 16 + j;
      if (gi < ne) {
        float* yrow = y + (size_t)(seg + gi) * D_DIM + cbase;
#pragma unroll
        for (int n = 0; n < 4; n++)
          yrow[n * 16] = acc[m][n][j] + bv[n];
      }
    }
  }
}

// ---------------- combine: out[t] = w0*y[p0] + w1*y[p1] ----------------
__global__ __launch_bounds__(256) void moe_combine(const float* __restrict__ y,
                                                   const int2* __restrict__ pos,
                                                   const float2* __restrict__ wts,
                                                   float* __restrict__ out) {
  int i = blockIdx.x * 256 + threadIdx.x;
  int idx = i * 4;
  int t = idx >> 10, d = idx & 1023;
  int2 p = pos[t];
  float2 w = wts[t];
  float4 a = *(const float4*)(y + (size_t)p.x * D_DIM + d);
  float4 b = *(const float4*)(y + (size_t)p.y * D_DIM + d);
  float4 o;
  o.x = w.x * a.x + w.y * b.x;
  o.y = w.x * a.y + w.y * b.y;
  o.z = w.x * a.z + w.y * b.z;
  o.w = w.x * a.w + w.y * b.w;
  *(float4*)(out + idx) = o;
}

extern "C" void kernel_launch(void* const* d_in, const int* in_sizes, int n_in,
                              void* d_out, int out_size, void* d_ws, size_t ws_size,
                              hipStream_t stream) {
  const float* x      = (const float*)d_in[0];
  const float* gate_w = (const float*)d_in[1];
  const float* gate_b = (const float*)d_in[2];
  const float* w1     = (const float*)d_in[3];
  const float* b1     = (const float*)d_in[4];
  const float* w2     = (const float*)d_in[5];
  const float* b2     = (const float*)d_in[6];
  float* out = (float*)d_out;

  uint8_t* ws = (uint8_t*)d_ws;
  unsigned short* hbuf = (unsigned short*)(ws);                 // 128 MiB
  unsigned short* xb   = (unsigned short*)(ws + 134217728ull);  // 16 MiB
  unsigned short* w1t  = (unsigned short*)(ws + 150994944ull);  // 64 MiB (overlaid with y)
  float*          yb   = (float*)         (ws + 150994944ull);  // y reuses w1t (dead after gemm1)
  unsigned short* w2t  = (unsigned short*)(ws + 218103808ull);  // 64 MiB
  int*    token_id = (int*)  (ws + 285212672ull);               // 64 KiB
  int2*   pos      = (int2*) (ws + 285278208ull);               // 64 KiB
  float2* wts      = (float2*)(ws + 285343744ull);              // 64 KiB
  int2*   sel      = (int2*) (ws + 285409280ull);               // 64 KiB
  int*    meta     = (int*)  (ws + 285474816ull);               // 512 B
  int2*   wl       = (int2*) (ws + 285475328ull);               // 2 KiB

  hipMemsetAsync(meta, 0, 512, stream);

  moe_gate_conv<<<dim3(T_TOK / 4), 256, 0, stream>>>(x, gate_w, gate_b, xb, sel, wts, meta);
  moe_transpose<<<dim3(H_DIM / 64, D_DIM / 64, E_NUM), 256, 0, stream>>>(w1, w1t, D_DIM, H_DIM);
  moe_transpose<<<dim3(D_DIM / 64, H_DIM / 64, E_NUM), 256, 0, stream>>>(w2, w2t, H_DIM, D_DIM);
  moe_scan<<<1, 64, 0, stream>>>(meta, wl);
  moe_scatter<<<dim3(T_TOK / 256), 256, 0, stream>>>(sel, meta, token_id, pos);
  moe_gemm1<<<dim3(H_DIM / 128, WL_MAX), 256, 0, stream>>>(xb, w1t, b1, meta, wl, token_id, hbuf);
  moe_gemm2<<<dim3(D_DIM / 128, WL_MAX), 256, 0, stream>>>(hbuf, w2t, b2, meta, wl, yb);
  moe_combine<<<dim3((T_TOK * D_DIM) / 1024), 256, 0, stream>>>(yb, pos, wts, out);
}